// Round 6
// baseline (125.093 us; speedup 1.0000x reference)
//
#include <hip/hip_runtime.h>

#define SEQ 8192
#define DM  128
#define NKS 8            // stored k-splits (1024 keys each)

typedef __attribute__((ext_vector_type(8)))  short bf16x8;
typedef __attribute__((ext_vector_type(16))) float f32x16;

static __device__ __forceinline__ unsigned short f2bf(float f) {
    unsigned int u = __builtin_bit_cast(unsigned int, f);
    u += 0x7FFFu + ((u >> 16) & 1u);
    return (unsigned short)(u >> 16);
}
static __device__ __forceinline__ unsigned int pack2bf(float a, float b) {
    return ((unsigned int)f2bf(b) << 16) | (unsigned int)f2bf(a);
}
static __device__ __forceinline__ float bflo(unsigned int u) {
    return __builtin_bit_cast(float, u << 16);
}
static __device__ __forceinline__ float bfhi(unsigned int u) {
    return __builtin_bit_cast(float, u & 0xFFFF0000u);
}
static __device__ __forceinline__ bf16x8 as_frag(uint4 v) {
    return __builtin_bit_cast(bf16x8, v);
}
static __device__ __forceinline__ unsigned int pack2bf_trunc(float a, float b) {
    return __builtin_amdgcn_perm(__builtin_bit_cast(unsigned int, b),
                                 __builtin_bit_cast(unsigned int, a), 0x07060302u);
}
static __device__ __forceinline__ void gl_lds16(const void* g, void* l) {
    __builtin_amdgcn_global_load_lds(
        (const __attribute__((address_space(1))) void*)(unsigned long long)g,
        (__attribute__((address_space(3))) void*)(unsigned int)(unsigned long long)l,
        16, 0, 0);
}
#define CL2 (1.4426950408889634f / 90.50966799187809f)   // log2(e)/sqrt(8192)

// ---- prep: 768 blocks; b<256: Q-tile, <512: K-tile, <768: V-tile ----------
// Fragment-order tiles (chunk p = s*64 + h*32 + q, 16B chunks):
//   Qt/Kt: chunk(p) = X[tile*32+q][16s+8h .. +8)   (Q pre-scaled by CL2)
//   Vt:    chunk(p) = V^T[32*(p64>>1)+q][tile*32 + 16*(p64&1)+8h .. +8)
// KV interleaved: KV[tile*1024 + p] = K chunks, + 512 + p = V chunks.
__global__ __launch_bounds__(256) void prep_kernel(
        const float* __restrict__ Q, const float* __restrict__ K,
        const float* __restrict__ V,
        uint4* __restrict__ Qt, uint4* __restrict__ KV) {
    __shared__ float TL[32 * 136];
    const int b = blockIdx.x, tid = threadIdx.x;
    const int which = b >> 8, tile = b & 255;
    const float4* S4 = (which == 0) ? (const float4*)Q
                     : (which == 1) ? (const float4*)K : (const float4*)V;
    #pragma unroll
    for (int u = 0; u < 4; ++u) {
        int f4 = u * 256 + tid;
        int k = f4 >> 5, c4 = f4 & 31;
        float4 v = S4[(size_t)tile * 1024 + f4];
        *(float4*)(TL + k * 136 + c4 * 4) = v;
    }
    __syncthreads();
    if (which < 2) {
        const float scale = (which == 0) ? (float)CL2 : 1.0f;
        uint4* dst = (which == 0) ? (Qt + (size_t)tile * 512)
                                  : (KV + (size_t)tile * 1024);
        #pragma unroll
        for (int u = 0; u < 2; ++u) {
            int p = u * 256 + tid;
            int q = p & 31, h = (p >> 5) & 1, s = p >> 6;
            const float* src = TL + q * 136 + s * 16 + h * 8;
            float4 a = *(const float4*)(src);
            float4 c = *(const float4*)(src + 4);
            dst[p] = make_uint4(pack2bf(a.x * scale, a.y * scale),
                                pack2bf(a.z * scale, a.w * scale),
                                pack2bf(c.x * scale, c.y * scale),
                                pack2bf(c.z * scale, c.w * scale));
        }
    } else {
        uint4* dst = KV + (size_t)tile * 1024 + 512;
        #pragma unroll
        for (int u = 0; u < 2; ++u) {
            int p = u * 256 + tid;
            int q = p & 31, h = (p >> 5) & 1, p64 = p >> 6;
            int d = (p64 >> 1) * 32 + q;
            int k0 = (p64 & 1) * 16 + h * 8;
            unsigned int r[4];
            #pragma unroll
            for (int jj = 0; jj < 4; ++jj)
                r[jj] = pack2bf(TL[(k0 + 2 * jj) * 136 + d],
                                TL[(k0 + 2 * jj + 1) * 136 + d]);
            dst[p] = make_uint4(r[0], r[1], r[2], r[3]);
        }
    }
}

// ---- main attention -------------------------------------------------------
// Grid 512 = 64 qt(128 q) x 8 ks(1024 keys); 2 WG/CU. Block 256 = 4 waves:
// (w&1)=q-half (64 q), (w>>1)=k-subslice (512 keys = 16 tiles of 32).
// KV tiles double-buffered in LDS per subslice; one barrier per iteration.
// k-subslice partials combined in-WG; stored splits = 8. No softmax max-shift
// (|scores| < ~1 at scale 1/sqrt(8192); exp cannot overflow).
__global__ __launch_bounds__(256, 2) void attn_kernel(
        const uint4* __restrict__ Qt, const uint4* __restrict__ KV,
        unsigned short* __restrict__ Opart, float* __restrict__ Lpart) {
    __shared__ __align__(16) uint4 kvbuf[2][2][1024];   // [ss][dbuf][chunk] 64 KB
    __shared__ float Lw[4][64];
    const int tid = threadIdx.x;
    const int w = tid >> 6, lane = tid & 63;
    const int q = lane & 31, h = lane >> 5;
    const int wq = w & 1, ss = w >> 1;
    const int ks = blockIdx.x & 7, qt = blockIdx.x >> 3;
    const int sub = qt * 2 + wq;                 // 64-q subtile id [0,128)

    // persistent Q fragments (two 32-q tiles) in registers
    uint4 qf0[8], qf1[8];
    {
        const uint4* qs = Qt + (size_t)(2 * sub) * 512 + lane;
        #pragma unroll
        for (int s = 0; s < 8; ++s) { qf0[s] = qs[s * 64]; qf1[s] = qs[512 + s * 64]; }
    }

    f32x16 oacc[8];          // a = g*4 + mb
    #pragma unroll
    for (int a = 0; a < 8; ++a)
        #pragma unroll
        for (int r = 0; r < 16; ++r) oacc[a][r] = 0.f;
    float ls0 = 0.f, ls1 = 0.f;

    // this subslice's 16 tiles; wave wq stages the wq-half (K or V) of each
    const uint4* kv0 = KV + ((size_t)(ks * 32 + ss * 16)) * 1024 + wq * 512;
    auto stage = [&](int buf, int t) {
        const uint4* src = kv0 + (size_t)t * 1024;
        uint4* dst = &kvbuf[ss][buf][wq * 512];
        #pragma unroll
        for (int u = 0; u < 8; ++u)
            gl_lds16(src + u * 64 + lane, dst + u * 64);
    };

    stage(0, 0);
    __syncthreads();
    #pragma unroll 1
    for (int t = 0; t < 16; ++t) {
        if (t < 15) stage((t + 1) & 1, t + 1);
        const uint4* kb = &kvbuf[ss][t & 1][0];

        f32x16 s0, s1;
        #pragma unroll
        for (int r = 0; r < 16; ++r) { s0[r] = 0.f; s1[r] = 0.f; }
        #pragma unroll
        for (int s = 0; s < 8; ++s) {
            uint4 kf = kb[s * 64 + lane];
            s0 = __builtin_amdgcn_mfma_f32_32x32x16_bf16(as_frag(kf), as_frag(qf0[s]), s0, 0, 0, 0);
            s1 = __builtin_amdgcn_mfma_f32_32x32x16_bf16(as_frag(kf), as_frag(qf1[s]), s1, 0, 0, 0);
        }

        #pragma unroll
        for (int g = 0; g < 2; ++g) {
            float p[16];
            #pragma unroll
            for (int r = 0; r < 16; ++r) {
                float sv = g ? s1[r] : s0[r];
                p[r] = __builtin_amdgcn_exp2f(sv);
                if (g) ls1 += p[r]; else ls0 += p[r];
            }
            unsigned int pk[8], px[8];
            #pragma unroll
            for (int jj = 0; jj < 8; ++jj) pk[jj] = pack2bf_trunc(p[2 * jj], p[2 * jj + 1]);
            #pragma unroll
            for (int jj = 0; jj < 8; ++jj) px[jj] = (unsigned int)__shfl_xor((int)pk[jj], 32);
            uint4 B0, B1;
            B0.x = h ? px[2] : pk[0];  B0.y = h ? px[3] : pk[1];
            B0.z = h ? pk[2] : px[0];  B0.w = h ? pk[3] : px[1];
            B1.x = h ? px[6] : pk[4];  B1.y = h ? px[7] : pk[5];
            B1.z = h ? pk[6] : px[4];  B1.w = h ? pk[7] : px[5];
            #pragma unroll
            for (int mb = 0; mb < 4; ++mb) {
                uint4 va = kb[512 + (2 * mb) * 64 + lane];
                uint4 vb = kb[512 + (2 * mb + 1) * 64 + lane];
                oacc[g * 4 + mb] = __builtin_amdgcn_mfma_f32_32x32x16_bf16(
                    as_frag(va), as_frag(B0), oacc[g * 4 + mb], 0, 0, 0);
                oacc[g * 4 + mb] = __builtin_amdgcn_mfma_f32_32x32x16_bf16(
                    as_frag(vb), as_frag(B1), oacc[g * 4 + mb], 0, 0, 0);
            }
        }
        __syncthreads();   // dbuf rotate: reads done + own staging drained
    }

    // ---- in-WG combine of k-subslices, then store 1 split per (ks,sub) ----
    float l0 = ls0 + __shfl_xor(ls0, 32);
    float l1 = ls1 + __shfl_xor(ls1, 32);
    if (h == 0) { Lw[w][q] = l0; Lw[w][32 + q] = l1; }
    if (w >= 2) {           // dump raw accs into dead kvbuf
        float* D = (float*)&kvbuf[0][0][0] + (w - 2) * 8192;
        #pragma unroll
        for (int a = 0; a < 8; ++a)
            #pragma unroll
            for (int r = 0; r < 16; ++r)
                D[(a * 16 + r) * 64 + lane] = oacc[a][r];
    }
    __syncthreads();
    if (w < 2) {
        const float* D = (const float*)&kvbuf[0][0][0] + w * 8192;
        #pragma unroll
        for (int a = 0; a < 8; ++a)
            #pragma unroll
            for (int r = 0; r < 16; ++r)
                oacc[a][r] += D[(a * 16 + r) * 64 + lane];
        if (h == 0) {
            Lpart[ks * SEQ + sub * 64 + q]      = l0 + Lw[w + 2][q];
            Lpart[ks * SEQ + sub * 64 + 32 + q] = l1 + Lw[w + 2][32 + q];
        }
        // raw-C-layout bf16 partial: elem = a*1024 + lane*16 + r
        unsigned short* dst = Opart + ((size_t)(ks * 128 + sub)) * 8192 + lane * 16;
        #pragma unroll
        for (int a = 0; a < 8; ++a) {
            unsigned int o[8];
            #pragma unroll
            for (int u = 0; u < 8; ++u)
                o[u] = pack2bf(oacc[a][2 * u], oacc[a][2 * u + 1]);
            *(uint4*)(dst + a * 1024)     = make_uint4(o[0], o[1], o[2], o[3]);
            *(uint4*)(dst + a * 1024 + 8) = make_uint4(o[4], o[5], o[6], o[7]);
        }
    }
}

// ---- reduce: 128 blocks (one 64-q subtile each): sum 8 splits, decode, ----
// transpose via LDS, normalize, store fp32 [q][d]
__global__ __launch_bounds__(256) void reduce_kernel(
        const unsigned short* __restrict__ Opart, const float* __restrict__ Lpart,
        float* __restrict__ Out) {
    __shared__ float T[64 * 132];
    __shared__ float Linv[64];
    const int tid = threadIdx.x, sub = blockIdx.x;
    if (tid < 64) {
        float L = 0.f;
        #pragma unroll
        for (int ks = 0; ks < NKS; ++ks) L += Lpart[ks * SEQ + sub * 64 + tid];
        Linv[tid] = 1.0f / L;
    }
    const int l = tid & 63, A = tid >> 6;       // owns accs a=2A, 2A+1
    float acc[32];
    #pragma unroll
    for (int u = 0; u < 32; ++u) acc[u] = 0.f;
    #pragma unroll 1
    for (int ks = 0; ks < NKS; ++ks) {
        const unsigned short* src = Opart + ((size_t)(ks * 128 + sub)) * 8192 + l * 16;
        #pragma unroll
        for (int ai = 0; ai < 2; ++ai) {
            const uint4* s4 = (const uint4*)(src + (2 * A + ai) * 1024);
            uint4 v0 = s4[0], v1 = *(const uint4*)((const unsigned short*)s4 + 8);
            float* a = acc + ai * 16;
            a[0] += bflo(v0.x);  a[1] += bfhi(v0.x);
            a[2] += bflo(v0.y);  a[3] += bfhi(v0.y);
            a[4] += bflo(v0.z);  a[5] += bfhi(v0.z);
            a[6] += bflo(v0.w);  a[7] += bfhi(v0.w);
            a[8] += bflo(v1.x);  a[9] += bfhi(v1.x);
            a[10] += bflo(v1.y); a[11] += bfhi(v1.y);
            a[12] += bflo(v1.z); a[13] += bfhi(v1.z);
            a[14] += bflo(v1.w); a[15] += bfhi(v1.w);
        }
    }
    const int hh = l >> 5;
    #pragma unroll
    for (int ai = 0; ai < 2; ++ai) {
        int a = 2 * A + ai;
        int q_loc = (a >> 2) * 32 + (l & 31);
        #pragma unroll
        for (int r = 0; r < 16; ++r) {
            int d = (a & 3) * 32 + (r & 3) + 8 * (r >> 2) + 4 * hh;
            T[q_loc * 132 + d] = acc[ai * 16 + r];
        }
    }
    __syncthreads();
    const int q_loc = tid >> 2, dseg = (tid & 3) * 32;
    const float rv = Linv[q_loc];
    #pragma unroll
    for (int c = 0; c < 8; ++c) {
        const float* tp = T + q_loc * 132 + dseg + c * 4;
        float4 o = make_float4(tp[0] * rv, tp[1] * rv, tp[2] * rv, tp[3] * rv);
        *(float4*)(Out + (size_t)(sub * 64 + q_loc) * DM + dseg + c * 4) = o;
    }
}

extern "C" void kernel_launch(void* const* d_in, const int* in_sizes, int n_in,
                              void* d_out, int out_size, void* d_ws, size_t ws_size,
                              hipStream_t stream) {
    const float* Q = (const float*)d_in[0];
    const float* K = (const float*)d_in[1];
    const float* V = (const float*)d_in[2];
    char* ws = (char*)d_ws;
    uint4* Qt            = (uint4*)ws;                                   // 2 MiB
    uint4* KV            = (uint4*)(ws + 2 * 1024 * 1024);               // 4 MiB
    float* Lpart         = (float*)(ws + 6 * 1024 * 1024);               // 256 KiB
    unsigned short* Opart= (unsigned short*)(ws + 6 * 1024 * 1024 + 262144); // 16 MiB
    float* Out = (float*)d_out;                     // total ws use: 22.25 MiB

    prep_kernel<<<768, 256, 0, stream>>>(Q, K, V, Qt, KV);
    attn_kernel<<<512, 256, 0, stream>>>(Qt, KV, Opart, Lpart);
    reduce_kernel<<<128, 256, 0, stream>>>(Opart, Lpart, Out);
}